// Round 3
// baseline (506.368 us; speedup 1.0000x reference)
//
#include <hip/hip_runtime.h>
#include <math.h>

// Problem constants
#define NB   256
#define TT   36
#define FF   50
#define PP   80
#define KK   161
#define NITER 100
#define LAMB 0.1f

#define CODE_SZ (NB*KK*FF)          // 2,060,800
#define D_OFF   CODE_SZ
#define R_OFF   (CODE_SZ + TT*KK)

// ws float layout:
// [1] = wn^2 accumulator; [16..79] = ssq partials (64 k_build blocks)
// [80..179] = beta momentum table (betas[it], it=1..99)
// [WSA1..] A1 image (D):   [Mt1:3][kt:6][h:2][512] f16 = 9216 floats
// [WSA2..] A2 image (D^T): [Mt2:6][kt:3][h:2][512] f16 = 9216 floats
#define WSA1 256
#define WSA2 (256 + 9216)

typedef _Float16 half8 __attribute__((ext_vector_type(8)));
typedef float f32x4  __attribute__((ext_vector_type(4)));
typedef float f32x16 __attribute__((ext_vector_type(16)));
#define MFMA_16(A,B,C) __builtin_amdgcn_mfma_f32_16x16x32_f16(A,B,C,0,0,0)
#define MFMA_32(A,B,C) __builtin_amdgcn_mfma_f32_32x32x16_f16(A,B,C,0,0,0)

// ---------------------------------------------------------------------------
// K1 (grid 64): build D (blk0 -> d_out), ssq partials -> ws[16+b], beta table
// (blk0 lane0 -> ws[80..179]), pack f16 hi/lo MFMA A-operand images for D
// (GEMM1 16x16x32) and D^T (GEMM2 32x32x16).
__global__ __launch_bounds__(256) void k_build(const float* __restrict__ rr,
                                               const float* __restrict__ th,
                                               float* __restrict__ out,
                                               float* __restrict__ ws) {
    __shared__ float Dl[TT*KK];
    __shared__ float red[256];
    int tid = threadIdx.x, b = blockIdx.x;
    for (int e = tid; e < TT*KK; e += 256) {
        int t = e / KK, k = e % KK;
        float v;
        if (k == 0) v = 1.f;
        else if (k <= PP) { int p = k - 1;     v = powf(rr[p], (float)t) * cosf((float)t * th[p]); }
        else              { int p = k - 1 - PP; v = powf(rr[p], (float)t) * sinf((float)t * th[p]); }
        Dl[e] = v;
        if (b == 0) out[D_OFF + e] = v;
    }
    // beta momentum table: identical float ops to the original in-loop chain
    if (b == 0 && tid == 0) {
        float t = 0.5f * (1.f + sqrtf(5.f));   // t_1 (after peeled iter 0)
        ws[80] = 0.f;
        for (int it = 1; it < NITER; ++it) {
            float tn = 0.5f * (1.f + sqrtf(1.f + 4.f*t*t));
            ws[80 + it] = (t - 1.f) / tn;
            t = tn;
        }
    }
    __syncthreads();
    float ssq = 0.f;
    for (int p = b*256 + tid; p < KK*KK; p += 64*256) {
        int k1 = p / KK, k2 = p % KK;
        float s = 0.f;
        for (int t = 0; t < TT; ++t) s += Dl[t*KK + k1] * Dl[t*KK + k2];
        ssq += s * s;
    }
    red[tid] = ssq;
    __syncthreads();
    for (int off = 128; off > 0; off >>= 1) {
        if (tid < off) red[tid] += red[tid + off];
        __syncthreads();
    }
    if (tid == 0) { ws[16 + b] = red[0]; if (b == 0) ws[1] = 0.f; }

    // A1: lane l holds A[m=l&15][k=8*(l>>4)+i] per 16x16x32 tile
    _Float16* a1 = (_Float16*)(ws + WSA1);
    for (int e = b*256 + tid; e < 3*6*2*512; e += 64*256) {
        int fp = e & 511, r = e >> 9;       // r = (Mt1*6+kt)*2 + h
        int h = r & 1, mk = r >> 1;
        int l = fp >> 3, i = fp & 7;
        int t = (mk / 6) * 16 + (l & 15);
        int j = (mk % 6) * 32 + ((l >> 4) << 3) + i;
        float v = (t < TT && j < KK) ? Dl[t*KK + j] : 0.f;
        _Float16 hi = (_Float16)v;
        a1[e] = h ? (_Float16)(v - (float)hi) : hi;
    }
    // A2 (D^T): lane l holds A[m=l&31][k=8*(l>>5)+i] per 32x32x16 tile
    _Float16* a2 = (_Float16*)(ws + WSA2);
    for (int e = b*256 + tid; e < 6*3*2*512; e += 64*256) {
        int fp = e & 511, r = e >> 9;       // r = (Mt2*3+kt)*2 + h
        int h = r & 1, mk = r >> 1;
        int l = fp >> 3, i = fp & 7;
        int m = (mk / 3) * 32 + (l & 31);
        int t = (mk % 3) * 16 + ((l >> 5) << 3) + i;
        float v = (m < KK && t < TT) ? Dl[t*KK + m] : 0.f;
        _Float16 hi = (_Float16)v;
        a2[e] = h ? (_Float16)(v - (float)hi) : hi;
    }
}

// ---------------------------------------------------------------------------
// K2: fused FISTA. f-columns are fully independent, so each n is split into
// TWO blocks of 32 columns (grid 512, 384 thr = 6 waves): two independent
// barrier groups per CU overlap each other's barrier/LDS-latency stalls
// (R2 counters: 31% issue-idle with one 12-wave lockstep group).
// GEMM1 (z = D y): 16x16x32, wave = (Mt1 = w>>1, nt1 = w&1).
// GEMM2 (w = D^T z): 32x32x16, wave = Mt2 = w.
template<int PHASE>
__global__ __launch_bounds__(384, 3) void k_fista(float* __restrict__ ws,
                                                  const float* __restrict__ x,
                                                  float* __restrict__ out) {
    __shared__ _Float16 Ys[2*6*512];   // 12,288 B: [nt16:2][kt32:6][512]
    __shared__ _Float16 Zs[3*512];     //  3,072 B: [kt16:3][512]
    __shared__ float bts[NITER];       //    400 B: beta momentum table
    int tid = threadIdx.x;
    int w = tid >> 6, l = tid & 63;
    int n = blockIdx.x >> 1, fhalf = blockIdx.x & 1;
    int fbase = fhalf << 5;

    // ---- stage x (32-col half) -> Zs (f16 hi, GEMM2 B-frag image, k-dim = t)
    const float* xb = x + n*TT*FF;
    for (int e = tid; e < 1536; e += 384) {
        int t = e >> 5, c = e & 31;
        float v = (t < TT && fbase + c < FF) ? xb[t*FF + fbase + c] : 0.f;
        int kt = t >> 4, kk = t & 15;
        int ofs = ((((kk >> 3) << 5) + c) << 3) + (kk & 7);
        Zs[(kt << 9) + ofs] = (_Float16)v;
    }
    if (tid < NITER) bts[tid] = ws[80 + tid];

    // ---- L-norm: wave butterfly over the 64 k_build partials
    float pv = ws[16 + l];
    #pragma unroll
    for (int off = 32; off > 0; off >>= 1) pv += __shfl_xor(pv, off);
    float linv = rsqrtf(pv);

    int Mt1 = w >> 1, nt1 = w & 1;     // GEMM1 role
    int Mt2 = w;                       // GEMM2 role
    const _Float16* a1g = (const _Float16*)(ws + WSA1);
    const _Float16* a2g = (const _Float16*)(ws + WSA2);
    half8 a1[6][2], a2[3][2];
    #pragma unroll
    for (int kt = 0; kt < 6; ++kt)
        #pragma unroll
        for (int h = 0; h < 2; ++h)
            a1[kt][h] = *(const half8*)(a1g + ((((Mt1*6 + kt)*2 + h) << 9) + (l << 3)));
    #pragma unroll
    for (int kt = 0; kt < 3; ++kt)
        #pragma unroll
        for (int h = 0; h < 2; ++h)
            a2[kt][h] = *(const half8*)(a2g + ((((Mt2*3 + kt)*2 + h) << 9) + (l << 3)));

    // held zero accumulators (loop-invariant C operands for first MFMA)
    f32x16 z16;
    #pragma unroll
    for (int r = 0; r < 16; ++r) z16[r] = 0.f;
    f32x4 z4 = {0.f, 0.f, 0.f, 0.f};
    __syncthreads();

    // ---- head GEMM2: acc = D^T @ f16(x)  (c-vector, registers only)
    f32x16 acc;
    {
        half8 bh = *(const half8*)&Zs[(0 << 9) + (l << 3)];
        acc = MFMA_32(a2[0][0], bh, z16);
        acc = MFMA_32(a2[0][1], bh, acc);
    }
    #pragma unroll
    for (int kt = 1; kt < 3; ++kt) {
        half8 bh = *(const half8*)&Zs[(kt << 9) + (l << 3)];
        acc = MFMA_32(a2[kt][0], bh, acc);
        acc = MFMA_32(a2[kt][1], bh, acc);
    }

    int cl = l & 15, q = l >> 4;       // GEMM1 C addressing
    int nloc = l & 31, s5 = l >> 5;    // GEMM2 C addressing
    int nt16 = nloc >> 4;
    int fcol = fbase + nloc;           // global f of owned columns
    int zofs = ((((q >> 1) << 5) + nt1*16 + cl) << 3) + ((q & 1) << 2);
    float cv[4][4], wl[4][4], xo[4][4], yo[4][4];
    float wlv = LAMB * linv;           // uniform shrink width (phase 0)

    // ---- peeled iteration 0: x1 = shrink(c), y1 = x1
    {
        float fac = 0.f;
        if (PHASE) fac = (float)KK * LAMB * linv * rsqrtf(ws[1]);
        #pragma unroll
        for (int gq = 0; gq < 4; ++gq) {
            int k0 = Mt2*32 + 8*gq + 4*s5;
            union { unsigned long long u; _Float16 hh[4]; } yh;
            #pragma unroll
            for (int j = 0; j < 4; ++j) {
                int k = k0 + j;
                float cvv = 0.f, wle;
                if (PHASE) {
                    wle = 0.f;
                    if (k < KK && fcol < FF) {
                        cvv = linv * acc[gq*4 + j];
                        float prev = out[(size_t)n*KK*FF + k*FF + fcol];
                        wle = fac / (fabsf(prev) + 0.01f);
                    }
                    wl[gq][j] = wle;
                } else {
                    wle = wlv;
                    if (k < KK && fcol < FF) cvv = linv * acc[gq*4 + j];
                }
                cv[gq][j] = cvv;
                float xn = cvv - __builtin_amdgcn_fmed3f(cvv, -wle, wle);
                xo[gq][j] = xn; yo[gq][j] = xn;
                yh.hh[j] = (_Float16)xn;
            }
            int yofs = ((gq*16 + cl) << 3) + (s5 << 2);
            *(unsigned long long*)&Ys[((nt16*6 + Mt2) << 9) + yofs] = yh.u;
        }
    }
    __syncthreads();

    for (int it = 1; it < NITER; ++it) {
        float beta = bts[it];
        // ---- GEMM1: z(Mt1, nt1) = D @ f16(y)  (single hi+lo chain)
        f32x4 zz;
        {
            half8 bh = *(const half8*)&Ys[((nt1*6 + 0) << 9) + (l << 3)];
            zz = MFMA_16(a1[0][0], bh, z4);
            zz = MFMA_16(a1[0][1], bh, zz);
        }
        #pragma unroll
        for (int kt = 1; kt < 6; ++kt) {
            half8 bh = *(const half8*)&Ys[((nt1*6 + kt) << 9) + (l << 3)];
            zz = MFMA_16(a1[kt][0], bh, zz);
            zz = MFMA_16(a1[kt][1], bh, zz);
        }
        {
            union { unsigned long long u; _Float16 hh[4]; } ph;
            #pragma unroll
            for (int r = 0; r < 4; ++r) ph.hh[r] = (_Float16)zz[r];
            *(unsigned long long*)&Zs[(Mt1 << 9) + zofs] = ph.u;
        }
        __syncthreads();

        // ---- GEMM2: acc(Mt2) = D^T @ f16(z)
        {
            half8 bh = *(const half8*)&Zs[(0 << 9) + (l << 3)];
            acc = MFMA_32(a2[0][0], bh, z16);
            acc = MFMA_32(a2[0][1], bh, acc);
        }
        #pragma unroll
        for (int kt = 1; kt < 3; ++kt) {
            half8 bh = *(const half8*)&Zs[(kt << 9) + (l << 3)];
            acc = MFMA_32(a2[kt][0], bh, acc);
            acc = MFMA_32(a2[kt][1], bh, acc);
        }
        // ---- epilogue: med3 shrink + momentum, rebuild y image (f16 hi)
        #pragma unroll
        for (int gq = 0; gq < 4; ++gq) {
            union { unsigned long long u; _Float16 hh[4]; } yh;
            #pragma unroll
            for (int j = 0; j < 4; ++j) {
                float ay = fmaf(-linv, acc[gq*4 + j], yo[gq][j]);
                float u  = ay + cv[gq][j];
                float wle = PHASE ? wl[gq][j] : wlv;
                float xn = u - __builtin_amdgcn_fmed3f(u, -wle, wle);
                float yn = fmaf(beta, xn - xo[gq][j], xn);
                xo[gq][j] = xn; yo[gq][j] = yn;
                yh.hh[j] = (_Float16)yn;
            }
            int yofs = ((gq*16 + cl) << 3) + (s5 << 2);
            *(unsigned long long*)&Ys[((nt16*6 + Mt2) << 9) + yofs] = yh.u;
        }
        __syncthreads();
    }

    // ---- store final code
    #pragma unroll
    for (int gq = 0; gq < 4; ++gq) {
        int k0 = Mt2*32 + 8*gq + 4*s5;
        #pragma unroll
        for (int j = 0; j < 4; ++j) {
            int k = k0 + j;
            if (k < KK && fcol < FF)
                out[(size_t)n*KK*FF + k*FF + fcol] = xo[gq][j];
        }
    }

    if (!PHASE) {
        // ---- fused wnorm
        float s = 0.f;
        #pragma unroll
        for (int gq = 0; gq < 4; ++gq) {
            int k0 = Mt2*32 + 8*gq + 4*s5;
            #pragma unroll
            for (int j = 0; j < 4; ++j) {
                if (k0 + j < KK && fcol < FF) {
                    float wn = 1.f / (fabsf(xo[gq][j]) + 0.01f);
                    s += wn * wn;
                }
            }
        }
        #pragma unroll
        for (int off = 32; off > 0; off >>= 1) s += __shfl_down(s, off);
        float* red = (float*)Zs;
        if (l == 0) red[w] = s;
        __syncthreads();
        if (tid == 0) {
            float t = 0.f;
            #pragma unroll
            for (int i = 0; i < 6; ++i) t += red[i];
            atomicAdd(&ws[1], t);
        }
    } else {
        // ---- fused reconst: f16(code) into Ys, GEMM1 pass, store
        #pragma unroll
        for (int gq = 0; gq < 4; ++gq) {
            union { unsigned long long u; _Float16 hh[4]; } yh;
            #pragma unroll
            for (int j = 0; j < 4; ++j) yh.hh[j] = (_Float16)xo[gq][j];
            int yofs = ((gq*16 + cl) << 3) + (s5 << 2);
            *(unsigned long long*)&Ys[((nt16*6 + Mt2) << 9) + yofs] = yh.u;
        }
        __syncthreads();
        f32x4 zz;
        {
            half8 bh = *(const half8*)&Ys[((nt1*6 + 0) << 9) + (l << 3)];
            zz = MFMA_16(a1[0][0], bh, z4);
            zz = MFMA_16(a1[0][1], bh, zz);
        }
        #pragma unroll
        for (int kt = 1; kt < 6; ++kt) {
            half8 bh = *(const half8*)&Ys[((nt1*6 + kt) << 9) + (l << 3)];
            zz = MFMA_16(a1[kt][0], bh, zz);
            zz = MFMA_16(a1[kt][1], bh, zz);
        }
        int fcol2 = fbase + nt1*16 + cl;
        #pragma unroll
        for (int r = 0; r < 4; ++r) {
            int t = Mt1*16 + q*4 + r;
            if (t < TT && fcol2 < FF)
                out[R_OFF + (size_t)n*TT*FF + t*FF + fcol2] = zz[r];
        }
    }
}

// ---------------------------------------------------------------------------
extern "C" void kernel_launch(void* const* d_in, const int* in_sizes, int n_in,
                              void* d_out, int out_size, void* d_ws, size_t ws_size,
                              hipStream_t stream) {
    const float* x  = (const float*)d_in[0];
    const float* rr = (const float*)d_in[1];
    const float* th = (const float*)d_in[2];
    float* out = (float*)d_out;
    float* ws  = (float*)d_ws;

    hipLaunchKernelGGL(k_build, dim3(64), dim3(256), 0, stream, rr, th, out, ws);
    hipLaunchKernelGGL(HIP_KERNEL_NAME(k_fista<0>), dim3(NB*2), dim3(384), 0, stream, ws, x, out);
    hipLaunchKernelGGL(HIP_KERNEL_NAME(k_fista<1>), dim3(NB*2), dim3(384), 0, stream, ws, x, out);
}

// Round 4
// 461.305 us; speedup vs baseline: 1.0977x; 1.0977x over previous
//
#include <hip/hip_runtime.h>
#include <math.h>

// Problem constants
#define NB   256
#define TT   36
#define FF   50
#define PP   80
#define KK   161
#define NITER 100
#define LAMB 0.1f

#define CODE_SZ (NB*KK*FF)          // 2,060,800
#define D_OFF   CODE_SZ
#define R_OFF   (CODE_SZ + TT*KK)

// ws float layout:
// [1] = wn^2 accumulator; [16..79] = ssq partials (64 k_build blocks)
// [80..179] = beta momentum table (betas[it], it=1..99)
// [WSA1..] A1 image (D):   [Mt1:3][kt:6][h:2][512] f16 = 9216 floats
// [WSA2..] A2 image (D^T): [Mt2:6][kt:3][h:2][512] f16 = 9216 floats
#define WSA1 256
#define WSA2 (256 + 9216)

typedef _Float16 half8 __attribute__((ext_vector_type(8)));
typedef float f32x4  __attribute__((ext_vector_type(4)));
typedef float f32x16 __attribute__((ext_vector_type(16)));
#define MFMA_16(A,B,C) __builtin_amdgcn_mfma_f32_16x16x32_f16(A,B,C,0,0,0)
#define MFMA_32(A,B,C) __builtin_amdgcn_mfma_f32_32x32x16_f16(A,B,C,0,0,0)

// ---------------------------------------------------------------------------
// K1 (grid 64): build D (blk0 -> d_out), ssq partials -> ws[16+b], beta table
// (blk0 lane0 -> ws[80..179]), pack f16 hi/lo MFMA A-operand images for D
// (GEMM1 16x16x32) and D^T (GEMM2 32x32x16).
__global__ __launch_bounds__(256) void k_build(const float* __restrict__ rr,
                                               const float* __restrict__ th,
                                               float* __restrict__ out,
                                               float* __restrict__ ws) {
    __shared__ float Dl[TT*KK];
    __shared__ float red[256];
    int tid = threadIdx.x, b = blockIdx.x;
    for (int e = tid; e < TT*KK; e += 256) {
        int t = e / KK, k = e % KK;
        float v;
        if (k == 0) v = 1.f;
        else if (k <= PP) { int p = k - 1;     v = powf(rr[p], (float)t) * cosf((float)t * th[p]); }
        else              { int p = k - 1 - PP; v = powf(rr[p], (float)t) * sinf((float)t * th[p]); }
        Dl[e] = v;
        if (b == 0) out[D_OFF + e] = v;
    }
    // beta momentum table: identical float ops to the original in-loop chain
    if (b == 0 && tid == 0) {
        float t = 0.5f * (1.f + sqrtf(5.f));   // t_1 (after peeled iter 0)
        ws[80] = 0.f;
        for (int it = 1; it < NITER; ++it) {
            float tn = 0.5f * (1.f + sqrtf(1.f + 4.f*t*t));
            ws[80 + it] = (t - 1.f) / tn;
            t = tn;
        }
    }
    __syncthreads();
    float ssq = 0.f;
    for (int p = b*256 + tid; p < KK*KK; p += 64*256) {
        int k1 = p / KK, k2 = p % KK;
        float s = 0.f;
        for (int t = 0; t < TT; ++t) s += Dl[t*KK + k1] * Dl[t*KK + k2];
        ssq += s * s;
    }
    red[tid] = ssq;
    __syncthreads();
    for (int off = 128; off > 0; off >>= 1) {
        if (tid < off) red[tid] += red[tid + off];
        __syncthreads();
    }
    if (tid == 0) { ws[16 + b] = red[0]; if (b == 0) ws[1] = 0.f; }

    // A1: lane l holds A[m=l&15][k=8*(l>>4)+i] per 16x16x32 tile
    _Float16* a1 = (_Float16*)(ws + WSA1);
    for (int e = b*256 + tid; e < 3*6*2*512; e += 64*256) {
        int fp = e & 511, r = e >> 9;       // r = (Mt1*6+kt)*2 + h
        int h = r & 1, mk = r >> 1;
        int l = fp >> 3, i = fp & 7;
        int t = (mk / 6) * 16 + (l & 15);
        int j = (mk % 6) * 32 + ((l >> 4) << 3) + i;
        float v = (t < TT && j < KK) ? Dl[t*KK + j] : 0.f;
        _Float16 hi = (_Float16)v;
        a1[e] = h ? (_Float16)(v - (float)hi) : hi;
    }
    // A2 (D^T): lane l holds A[m=l&31][k=8*(l>>5)+i] per 32x32x16 tile
    _Float16* a2 = (_Float16*)(ws + WSA2);
    for (int e = b*256 + tid; e < 6*3*2*512; e += 64*256) {
        int fp = e & 511, r = e >> 9;       // r = (Mt2*3+kt)*2 + h
        int h = r & 1, mk = r >> 1;
        int l = fp >> 3, i = fp & 7;
        int m = (mk / 3) * 32 + (l & 31);
        int t = (mk % 3) * 16 + ((l >> 5) << 3) + i;
        float v = (m < KK && t < TT) ? Dl[t*KK + m] : 0.f;
        _Float16 hi = (_Float16)v;
        a2[e] = h ? (_Float16)(v - (float)hi) : hi;
    }
}

// ---------------------------------------------------------------------------
// K2: fused FISTA, grid 256 (one n per block), 768 threads = 12 waves.
// R3 lesson: 384-thr split blocks do NOT co-reside (1 blk/CU, sequential
// rounds) -> revert to 768. R3 solo-block data exposed the latency chain:
// single-accumulator GEMMs serialize 12 (GEMM1) / 6 (GEMM2) dependent MFMAs
// (~240/~205 cyc). Split each GEMM into hi/lo independent chains merged by a
// vector add: critical path per iter ~1050 -> ~820 cyc.
// GEMM1 (z = D y): 16x16x32, wave = (Mt1 = w>>2, nt1 = w&3).
// GEMM2 (w = D^T z): 32x32x16, wave = (Mt2 = w>>1, nh = w&1).
template<int PHASE>
__global__ __launch_bounds__(768, 3) void k_fista(float* __restrict__ ws,
                                                  const float* __restrict__ x,
                                                  float* __restrict__ out) {
    __shared__ _Float16 Ys[4*6*512];   // 24,576 B: [nt16:4][kt32:6][512]
    __shared__ _Float16 Zs[2*3*512];   //  6,144 B: [nh:2][kt16:3][512]
    __shared__ float bts[NITER];       //    400 B: beta momentum table
    int tid = threadIdx.x;
    int w = tid >> 6, l = tid & 63;
    int n = blockIdx.x;

    // ---- stage x -> Zs (f16 hi, GEMM2 B-frag image, k-dim = t)
    const float* xb = x + n*TT*FF;
    for (int e = tid; e < 3072; e += 768) {
        int t = e >> 6, c64 = e & 63;
        float v = (t < TT && c64 < FF) ? xb[t*FF + c64] : 0.f;
        int nh = c64 >> 5, c = c64 & 31;
        int kt = t >> 4, kk = t & 15;
        int ofs = ((((kk >> 3) << 5) + c) << 3) + (kk & 7);
        Zs[((nh*3 + kt) << 9) + ofs] = (_Float16)v;
    }
    if (tid < NITER) bts[tid] = ws[80 + tid];

    // ---- L-norm: wave butterfly over the 64 k_build partials
    float pv = ws[16 + l];
    #pragma unroll
    for (int off = 32; off > 0; off >>= 1) pv += __shfl_xor(pv, off);
    float linv = rsqrtf(pv);

    int Mt1 = w >> 2, nt1 = w & 3;     // GEMM1 role
    int Mt2 = w >> 1, nh  = w & 1;     // GEMM2 role
    const _Float16* a1g = (const _Float16*)(ws + WSA1);
    const _Float16* a2g = (const _Float16*)(ws + WSA2);
    half8 a1[6][2], a2[3][2];
    #pragma unroll
    for (int kt = 0; kt < 6; ++kt)
        #pragma unroll
        for (int h = 0; h < 2; ++h)
            a1[kt][h] = *(const half8*)(a1g + ((((Mt1*6 + kt)*2 + h) << 9) + (l << 3)));
    #pragma unroll
    for (int kt = 0; kt < 3; ++kt)
        #pragma unroll
        for (int h = 0; h < 2; ++h)
            a2[kt][h] = *(const half8*)(a2g + ((((Mt2*3 + kt)*2 + h) << 9) + (l << 3)));

    // held zero accumulators (loop-invariant C operands for first MFMA)
    f32x16 z16;
    #pragma unroll
    for (int r = 0; r < 16; ++r) z16[r] = 0.f;
    f32x4 z4 = {0.f, 0.f, 0.f, 0.f};
    __syncthreads();

    // ---- head GEMM2: acc = D^T @ f16(x)  (2 independent hi/lo chains)
    f32x16 acc;
    {
        f32x16 acch, accl;
        {
            half8 bh = *(const half8*)&Zs[((nh*3 + 0) << 9) + (l << 3)];
            acch = MFMA_32(a2[0][0], bh, z16);
            accl = MFMA_32(a2[0][1], bh, z16);
        }
        #pragma unroll
        for (int kt = 1; kt < 3; ++kt) {
            half8 bh = *(const half8*)&Zs[((nh*3 + kt) << 9) + (l << 3)];
            acch = MFMA_32(a2[kt][0], bh, acch);
            accl = MFMA_32(a2[kt][1], bh, accl);
        }
        acc = acch + accl;
    }

    int cl = l & 15, q = l >> 4;       // GEMM1 C addressing
    int nloc = l & 31, s5 = l >> 5;    // GEMM2 C addressing
    int nt16 = nh*2 + (nloc >> 4);
    int fcol = nh*32 + nloc;           // global f of owned columns
    int zofs = ((((q >> 1) << 5) + (nt1 & 1)*16 + cl) << 3) + ((q & 1) << 2);
    int znh = nt1 >> 1;
    float cv[4][4], wl[4][4], xo[4][4], yo[4][4];
    float wlv = LAMB * linv;           // uniform shrink width (phase 0)

    // ---- peeled iteration 0: x1 = shrink(c), y1 = x1
    {
        float fac = 0.f;
        if (PHASE) fac = (float)KK * LAMB * linv * rsqrtf(ws[1]);
        #pragma unroll
        for (int gq = 0; gq < 4; ++gq) {
            int k0 = Mt2*32 + 8*gq + 4*s5;
            union { unsigned long long u; _Float16 hh[4]; } yh;
            #pragma unroll
            for (int j = 0; j < 4; ++j) {
                int k = k0 + j;
                float cvv = 0.f, wle;
                if (PHASE) {
                    wle = 0.f;
                    if (k < KK && fcol < FF) {
                        cvv = linv * acc[gq*4 + j];
                        float prev = out[(size_t)n*KK*FF + k*FF + fcol];
                        wle = fac / (fabsf(prev) + 0.01f);
                    }
                    wl[gq][j] = wle;
                } else {
                    wle = wlv;
                    if (k < KK && fcol < FF) cvv = linv * acc[gq*4 + j];
                }
                cv[gq][j] = cvv;
                float xn = cvv - __builtin_amdgcn_fmed3f(cvv, -wle, wle);
                xo[gq][j] = xn; yo[gq][j] = xn;
                yh.hh[j] = (_Float16)xn;
            }
            int yofs = ((gq*16 + cl) << 3) + (s5 << 2);
            *(unsigned long long*)&Ys[((nt16*6 + Mt2) << 9) + yofs] = yh.u;
        }
    }
    __syncthreads();

    for (int it = 1; it < NITER; ++it) {
        float beta = bts[it];
        // ---- GEMM1: z(Mt1, nt1) = D @ f16(y)  (2 independent hi/lo chains)
        f32x4 za, zb;
        {
            half8 bh = *(const half8*)&Ys[((nt1*6 + 0) << 9) + (l << 3)];
            za = MFMA_16(a1[0][0], bh, z4);
            zb = MFMA_16(a1[0][1], bh, z4);
        }
        #pragma unroll
        for (int kt = 1; kt < 6; ++kt) {
            half8 bh = *(const half8*)&Ys[((nt1*6 + kt) << 9) + (l << 3)];
            za = MFMA_16(a1[kt][0], bh, za);
            zb = MFMA_16(a1[kt][1], bh, zb);
        }
        f32x4 zz = za + zb;
        {
            union { unsigned long long u; _Float16 hh[4]; } ph;
            #pragma unroll
            for (int r = 0; r < 4; ++r) ph.hh[r] = (_Float16)zz[r];
            *(unsigned long long*)&Zs[((znh*3 + Mt1) << 9) + zofs] = ph.u;
        }
        __syncthreads();

        // ---- GEMM2: acc(Mt2, nh) = D^T @ f16(z)  (2 independent chains)
        f32x16 acch, accl;
        {
            half8 bh = *(const half8*)&Zs[((nh*3 + 0) << 9) + (l << 3)];
            acch = MFMA_32(a2[0][0], bh, z16);
            accl = MFMA_32(a2[0][1], bh, z16);
        }
        #pragma unroll
        for (int kt = 1; kt < 3; ++kt) {
            half8 bh = *(const half8*)&Zs[((nh*3 + kt) << 9) + (l << 3)];
            acch = MFMA_32(a2[kt][0], bh, acch);
            accl = MFMA_32(a2[kt][1], bh, accl);
        }
        acc = acch + accl;
        // ---- epilogue: med3 shrink + momentum, rebuild y image (f16 hi)
        #pragma unroll
        for (int gq = 0; gq < 4; ++gq) {
            union { unsigned long long u; _Float16 hh[4]; } yh;
            #pragma unroll
            for (int j = 0; j < 4; ++j) {
                float ay = fmaf(-linv, acc[gq*4 + j], yo[gq][j]);
                float u  = ay + cv[gq][j];
                float wle = PHASE ? wl[gq][j] : wlv;
                float xn = u - __builtin_amdgcn_fmed3f(u, -wle, wle);
                float yn = fmaf(beta, xn - xo[gq][j], xn);
                xo[gq][j] = xn; yo[gq][j] = yn;
                yh.hh[j] = (_Float16)yn;
            }
            int yofs = ((gq*16 + cl) << 3) + (s5 << 2);
            *(unsigned long long*)&Ys[((nt16*6 + Mt2) << 9) + yofs] = yh.u;
        }
        __syncthreads();
    }

    // ---- store final code
    #pragma unroll
    for (int gq = 0; gq < 4; ++gq) {
        int k0 = Mt2*32 + 8*gq + 4*s5;
        #pragma unroll
        for (int j = 0; j < 4; ++j) {
            int k = k0 + j;
            if (k < KK && fcol < FF)
                out[(size_t)n*KK*FF + k*FF + fcol] = xo[gq][j];
        }
    }

    if (!PHASE) {
        // ---- fused wnorm
        float s = 0.f;
        #pragma unroll
        for (int gq = 0; gq < 4; ++gq) {
            int k0 = Mt2*32 + 8*gq + 4*s5;
            #pragma unroll
            for (int j = 0; j < 4; ++j) {
                if (k0 + j < KK && fcol < FF) {
                    float wn = 1.f / (fabsf(xo[gq][j]) + 0.01f);
                    s += wn * wn;
                }
            }
        }
        #pragma unroll
        for (int off = 32; off > 0; off >>= 1) s += __shfl_down(s, off);
        float* red = (float*)Zs;
        if (l == 0) red[w] = s;
        __syncthreads();
        if (tid == 0) {
            float t = 0.f;
            #pragma unroll
            for (int i = 0; i < 12; ++i) t += red[i];
            atomicAdd(&ws[1], t);
        }
    } else {
        // ---- fused reconst: f16(code) into Ys, GEMM1 pass, store
        #pragma unroll
        for (int gq = 0; gq < 4; ++gq) {
            union { unsigned long long u; _Float16 hh[4]; } yh;
            #pragma unroll
            for (int j = 0; j < 4; ++j) yh.hh[j] = (_Float16)xo[gq][j];
            int yofs = ((gq*16 + cl) << 3) + (s5 << 2);
            *(unsigned long long*)&Ys[((nt16*6 + Mt2) << 9) + yofs] = yh.u;
        }
        __syncthreads();
        f32x4 za, zb;
        {
            half8 bh = *(const half8*)&Ys[((nt1*6 + 0) << 9) + (l << 3)];
            za = MFMA_16(a1[0][0], bh, z4);
            zb = MFMA_16(a1[0][1], bh, z4);
        }
        #pragma unroll
        for (int kt = 1; kt < 6; ++kt) {
            half8 bh = *(const half8*)&Ys[((nt1*6 + kt) << 9) + (l << 3)];
            za = MFMA_16(a1[kt][0], bh, za);
            zb = MFMA_16(a1[kt][1], bh, zb);
        }
        f32x4 zz = za + zb;
        int fcol2 = nt1*16 + cl;
        #pragma unroll
        for (int r = 0; r < 4; ++r) {
            int t = Mt1*16 + q*4 + r;
            if (t < TT && fcol2 < FF)
                out[R_OFF + (size_t)n*TT*FF + t*FF + fcol2] = zz[r];
        }
    }
}

// ---------------------------------------------------------------------------
extern "C" void kernel_launch(void* const* d_in, const int* in_sizes, int n_in,
                              void* d_out, int out_size, void* d_ws, size_t ws_size,
                              hipStream_t stream) {
    const float* x  = (const float*)d_in[0];
    const float* rr = (const float*)d_in[1];
    const float* th = (const float*)d_in[2];
    float* out = (float*)d_out;
    float* ws  = (float*)d_ws;

    hipLaunchKernelGGL(k_build, dim3(64), dim3(256), 0, stream, rr, th, out, ws);
    hipLaunchKernelGGL(HIP_KERNEL_NAME(k_fista<0>), dim3(NB), dim3(768), 0, stream, ws, x, out);
    hipLaunchKernelGGL(HIP_KERNEL_NAME(k_fista<1>), dim3(NB), dim3(768), 0, stream, ws, x, out);
}

// Round 5
// 374.904 us; speedup vs baseline: 1.3507x; 1.2305x over previous
//
#include <hip/hip_runtime.h>
#include <math.h>

// Problem constants
#define NB   256
#define TT   36
#define FF   50
#define PP   80
#define KK   161
#define NITER 100
#define LAMB 0.1f

#define CODE_SZ (NB*KK*FF)          // 2,060,800
#define D_OFF   CODE_SZ
#define R_OFF   (CODE_SZ + TT*KK)

// ws float layout:
// [1] = wn^2 accumulator; [16..79] = ssq partials (64 k_build blocks)
// [80..179] = beta momentum table (betas[it], it=1..99)
// [WSA1..] A1 image (D):   [Mt1:3][kt:6][h:2][512] f16 = 9216 floats
// [WSA2..] A2 image (D^T): [Mt2:6][kt:3][h:2][512] f16 = 9216 floats
#define WSA1 256
#define WSA2 (256 + 9216)

// LDS bank swizzles (half-element index units). Bijective XOR of a high
// address bit into bit3 (8 halfs = 16 B): spreads the 4-lane write-aliasing
// groups {l,l+16} (Ys: +6 segs -> half-bit10) and {l,l+32} (Zs: +256 halfs
// -> half-bit8) across distinct banks. All applied offsets loop-invariant.
#define SWZY(i) ((i) ^ ((((i) >> 10) & 1) << 3))
#define SWZZ(i) ((i) ^ ((((i) >> 8) & 1) << 3))

typedef _Float16 half8 __attribute__((ext_vector_type(8)));
typedef float f32x4  __attribute__((ext_vector_type(4)));
typedef float f32x16 __attribute__((ext_vector_type(16)));
#define MFMA_16(A,B,C) __builtin_amdgcn_mfma_f32_16x16x32_f16(A,B,C,0,0,0)
#define MFMA_32(A,B,C) __builtin_amdgcn_mfma_f32_32x32x16_f16(A,B,C,0,0,0)

// ---------------------------------------------------------------------------
// K1 (grid 64): build D (blk0 -> d_out), ssq partials -> ws[16+b], beta table
// (blk0 lane0 -> ws[80..179]), pack f16 hi/lo MFMA A-operand images for D
// (GEMM1 16x16x32) and D^T (GEMM2 32x32x16).
__global__ __launch_bounds__(256) void k_build(const float* __restrict__ rr,
                                               const float* __restrict__ th,
                                               float* __restrict__ out,
                                               float* __restrict__ ws) {
    __shared__ float Dl[TT*KK];
    __shared__ float red[256];
    int tid = threadIdx.x, b = blockIdx.x;
    for (int e = tid; e < TT*KK; e += 256) {
        int t = e / KK, k = e % KK;
        float v;
        if (k == 0) v = 1.f;
        else if (k <= PP) { int p = k - 1;     v = powf(rr[p], (float)t) * cosf((float)t * th[p]); }
        else              { int p = k - 1 - PP; v = powf(rr[p], (float)t) * sinf((float)t * th[p]); }
        Dl[e] = v;
        if (b == 0) out[D_OFF + e] = v;
    }
    // beta momentum table: identical float ops to the original in-loop chain
    if (b == 0 && tid == 0) {
        float t = 0.5f * (1.f + sqrtf(5.f));   // t_1 (after peeled iter 0)
        ws[80] = 0.f;
        for (int it = 1; it < NITER; ++it) {
            float tn = 0.5f * (1.f + sqrtf(1.f + 4.f*t*t));
            ws[80 + it] = (t - 1.f) / tn;
            t = tn;
        }
    }
    __syncthreads();
    float ssq = 0.f;
    for (int p = b*256 + tid; p < KK*KK; p += 64*256) {
        int k1 = p / KK, k2 = p % KK;
        float s = 0.f;
        for (int t = 0; t < TT; ++t) s += Dl[t*KK + k1] * Dl[t*KK + k2];
        ssq += s * s;
    }
    red[tid] = ssq;
    __syncthreads();
    for (int off = 128; off > 0; off >>= 1) {
        if (tid < off) red[tid] += red[tid + off];
        __syncthreads();
    }
    if (tid == 0) { ws[16 + b] = red[0]; if (b == 0) ws[1] = 0.f; }

    // A1: lane l holds A[m=l&15][k=8*(l>>4)+i] per 16x16x32 tile
    _Float16* a1 = (_Float16*)(ws + WSA1);
    for (int e = b*256 + tid; e < 3*6*2*512; e += 64*256) {
        int fp = e & 511, r = e >> 9;       // r = (Mt1*6+kt)*2 + h
        int h = r & 1, mk = r >> 1;
        int l = fp >> 3, i = fp & 7;
        int t = (mk / 6) * 16 + (l & 15);
        int j = (mk % 6) * 32 + ((l >> 4) << 3) + i;
        float v = (t < TT && j < KK) ? Dl[t*KK + j] : 0.f;
        _Float16 hi = (_Float16)v;
        a1[e] = h ? (_Float16)(v - (float)hi) : hi;
    }
    // A2 (D^T): lane l holds A[m=l&31][k=8*(l>>5)+i] per 32x32x16 tile
    _Float16* a2 = (_Float16*)(ws + WSA2);
    for (int e = b*256 + tid; e < 6*3*2*512; e += 64*256) {
        int fp = e & 511, r = e >> 9;       // r = (Mt2*3+kt)*2 + h
        int h = r & 1, mk = r >> 1;
        int l = fp >> 3, i = fp & 7;
        int m = (mk / 3) * 32 + (l & 31);
        int t = (mk % 3) * 16 + ((l >> 5) << 3) + i;
        float v = (m < KK && t < TT) ? Dl[t*KK + m] : 0.f;
        _Float16 hi = (_Float16)v;
        a2[e] = h ? (_Float16)(v - (float)hi) : hi;
    }
}

// ---------------------------------------------------------------------------
// K2: fused FISTA, grid 256 (one n per block), 768 threads = 12 waves.
// R4 lesson: dual accumulator chains -> AGPR/scratch spills (FETCH 4.5x).
// R5 model: LDS-pipe-BW-bound (~138 KB/iter/CU = ~1080 cyc at 128 B/clk).
// Cuts: kt5-trim of GEMM1 (K 161 pads to 192; kt5 holds only k=160 ->
// exact rank-1 fixup, -12 KB), dead-write skips (-4.5 KB), XOR bank
// swizzles on Ys/Zs to kill the 4-lane write aliasing.
// GEMM1 (z = D y): 16x16x32, wave = (Mt1 = w>>2, nt1 = w&3).
// GEMM2 (w = D^T z): 32x32x16, wave = (Mt2 = w>>1, nh = w&1).
template<int PHASE>
__global__ __launch_bounds__(768, 3) void k_fista(float* __restrict__ ws,
                                                  const float* __restrict__ x,
                                                  float* __restrict__ out) {
    __shared__ _Float16 Ys[4*6*512];   // 24,576 B: [nt16:4][kt32:6][512]
    __shared__ _Float16 Zs[2*3*512];   //  6,144 B: [nh:2][kt16:3][512]
    __shared__ float bts[NITER];       //    400 B: beta momentum table
    int tid = threadIdx.x;
    int w = tid >> 6, l = tid & 63;
    int n = blockIdx.x;

    // ---- stage x -> Zs (f16 hi, GEMM2 B-frag image, k-dim = t)
    const float* xb = x + n*TT*FF;
    for (int e = tid; e < 3072; e += 768) {
        int t = e >> 6, c64 = e & 63;
        float v = (t < TT && c64 < FF) ? xb[t*FF + c64] : 0.f;
        int nh = c64 >> 5, c = c64 & 31;
        int kt = t >> 4, kk = t & 15;
        int ofs = ((((kk >> 3) << 5) + c) << 3) + (kk & 7);
        Zs[SWZZ(((nh*3 + kt) << 9) + ofs)] = (_Float16)v;
    }
    if (tid < NITER) bts[tid] = ws[80 + tid];

    // ---- L-norm: wave butterfly over the 64 k_build partials
    float pv = ws[16 + l];
    #pragma unroll
    for (int off = 32; off > 0; off >>= 1) pv += __shfl_xor(pv, off);
    float linv = rsqrtf(pv);

    int Mt1 = w >> 2, nt1 = w & 3;     // GEMM1 role
    int Mt2 = w >> 1, nh  = w & 1;     // GEMM2 role
    const _Float16* a1g = (const _Float16*)(ws + WSA1);
    const _Float16* a2g = (const _Float16*)(ws + WSA2);
    half8 a1[5][2], a2[3][2];
    #pragma unroll
    for (int kt = 0; kt < 5; ++kt)     // kt5 trimmed (rank-1 fixup instead)
        #pragma unroll
        for (int h = 0; h < 2; ++h)
            a1[kt][h] = *(const half8*)(a1g + ((((Mt1*6 + kt)*2 + h) << 9) + (l << 3)));
    #pragma unroll
    for (int kt = 0; kt < 3; ++kt)
        #pragma unroll
        for (int h = 0; h < 2; ++h)
            a2[kt][h] = *(const half8*)(a2g + ((((Mt2*3 + kt)*2 + h) << 9) + (l << 3)));

    int cl = l & 15, q = l >> 4;       // GEMM1 C addressing
    // rank-1 fixup data: D column 160 for this lane's 4 output rows
    float dcol[4];
    #pragma unroll
    for (int r = 0; r < 4; ++r) {
        int t = Mt1*16 + q*4 + r;
        dcol[r] = (t < TT) ? out[D_OFF + t*KK + 160] : 0.f;
    }
    int y160i = SWZY(((nt1*6 + 5) << 9) + (cl << 3)); // Ys slot of y[160, nt1*16+cl]

    // held zero accumulators (loop-invariant C operands for first MFMA)
    f32x16 z16;
    #pragma unroll
    for (int r = 0; r < 16; ++r) z16[r] = 0.f;
    f32x4 z4 = {0.f, 0.f, 0.f, 0.f};
    __syncthreads();

    // ---- head GEMM2: acc = D^T @ f16(x)  (c-vector, registers only)
    f32x16 acc;
    {
        half8 bh = *(const half8*)&Zs[SWZZ(((nh*3 + 0) << 9) + (l << 3))];
        acc = MFMA_32(a2[0][0], bh, z16);
        acc = MFMA_32(a2[0][1], bh, acc);
    }
    #pragma unroll
    for (int kt = 1; kt < 3; ++kt) {
        half8 bh = *(const half8*)&Zs[SWZZ(((nh*3 + kt) << 9) + (l << 3))];
        acc = MFMA_32(a2[kt][0], bh, acc);
        acc = MFMA_32(a2[kt][1], bh, acc);
    }

    int nloc = l & 31, s5 = l >> 5;    // GEMM2 C addressing
    int nt16 = nh*2 + (nloc >> 4);
    int fcol = nh*32 + nloc;           // global f of owned columns
    int zofs = ((((q >> 1) << 5) + (nt1 & 1)*16 + cl) << 3) + ((q & 1) << 2);
    int znh = nt1 >> 1;
    int zidx = SWZZ(((znh*3 + Mt1) << 9) + zofs);
    float cv[4][4], wl[4][4], xo[4][4], yo[4][4];
    float wlv = LAMB * linv;           // uniform shrink width (phase 0)

    // ---- peeled iteration 0: x1 = shrink(c), y1 = x1
    {
        float fac = 0.f;
        if (PHASE) fac = (float)KK * LAMB * linv * rsqrtf(ws[1]);
        #pragma unroll
        for (int gq = 0; gq < 4; ++gq) {
            int k0 = Mt2*32 + 8*gq + 4*s5;
            union { unsigned long long u; _Float16 hh[4]; } yh;
            #pragma unroll
            for (int j = 0; j < 4; ++j) {
                int k = k0 + j;
                float cvv = 0.f, wle;
                if (PHASE) {
                    wle = 0.f;
                    if (k < KK && fcol < FF) {
                        cvv = linv * acc[gq*4 + j];
                        float prev = out[(size_t)n*KK*FF + k*FF + fcol];
                        wle = fac / (fabsf(prev) + 0.01f);
                    }
                    wl[gq][j] = wle;
                } else {
                    wle = wlv;
                    if (k < KK && fcol < FF) cvv = linv * acc[gq*4 + j];
                }
                cv[gq][j] = cvv;
                float xn = cvv - __builtin_amdgcn_fmed3f(cvv, -wle, wle);
                xo[gq][j] = xn; yo[gq][j] = xn;
                yh.hh[j] = (_Float16)xn;
            }
            int yofs = ((gq*16 + cl) << 3) + (s5 << 2);
            *(unsigned long long*)&Ys[SWZY(((nt16*6 + Mt2) << 9) + yofs)] = yh.u;
        }
    }
    __syncthreads();

    for (int it = 1; it < NITER; ++it) {
        float beta = bts[it];
        // ---- GEMM1: z(Mt1, nt1) = D @ f16(y)  (5 kt + rank-1 k=160 fixup)
        f32x4 zz;
        {
            half8 bh = *(const half8*)&Ys[SWZY(((nt1*6 + 0) << 9) + (l << 3))];
            zz = MFMA_16(a1[0][0], bh, z4);
            zz = MFMA_16(a1[0][1], bh, zz);
        }
        #pragma unroll
        for (int kt = 1; kt < 5; ++kt) {
            half8 bh = *(const half8*)&Ys[SWZY(((nt1*6 + kt) << 9) + (l << 3))];
            zz = MFMA_16(a1[kt][0], bh, zz);
            zz = MFMA_16(a1[kt][1], bh, zz);
        }
        {
            float y160f = (float)Ys[y160i];
            #pragma unroll
            for (int r = 0; r < 4; ++r) zz[r] = fmaf(dcol[r], y160f, zz[r]);
        }
        if (Mt1 < 2 || q == 0) {       // z rows 36-47 stay zero (staged)
            union { unsigned long long u; _Float16 hh[4]; } ph;
            #pragma unroll
            for (int r = 0; r < 4; ++r) ph.hh[r] = (_Float16)zz[r];
            *(unsigned long long*)&Zs[zidx] = ph.u;
        }
        __syncthreads();

        // ---- GEMM2: acc(Mt2, nh) = D^T @ f16(z)
        {
            half8 bh = *(const half8*)&Zs[SWZZ(((nh*3 + 0) << 9) + (l << 3))];
            acc = MFMA_32(a2[0][0], bh, z16);
            acc = MFMA_32(a2[0][1], bh, acc);
        }
        #pragma unroll
        for (int kt = 1; kt < 3; ++kt) {
            half8 bh = *(const half8*)&Zs[SWZZ(((nh*3 + kt) << 9) + (l << 3))];
            acc = MFMA_32(a2[kt][0], bh, acc);
            acc = MFMA_32(a2[kt][1], bh, acc);
        }
        // ---- epilogue: med3 shrink + momentum, rebuild y image (f16 hi)
        #pragma unroll
        for (int gq = 0; gq < 4; ++gq) {
            union { unsigned long long u; _Float16 hh[4]; } yh;
            #pragma unroll
            for (int j = 0; j < 4; ++j) {
                float ay = fmaf(-linv, acc[gq*4 + j], yo[gq][j]);
                float u  = ay + cv[gq][j];
                float wle = PHASE ? wl[gq][j] : wlv;
                float xn = u - __builtin_amdgcn_fmed3f(u, -wle, wle);
                float yn = fmaf(beta, xn - xo[gq][j], xn);
                xo[gq][j] = xn; yo[gq][j] = yn;
                yh.hh[j] = (_Float16)yn;
            }
            if (Mt2 < 5 || gq == 0) {  // k 168-191 never read
                int yofs = ((gq*16 + cl) << 3) + (s5 << 2);
                *(unsigned long long*)&Ys[SWZY(((nt16*6 + Mt2) << 9) + yofs)] = yh.u;
            }
        }
        __syncthreads();
    }

    // ---- store final code
    #pragma unroll
    for (int gq = 0; gq < 4; ++gq) {
        int k0 = Mt2*32 + 8*gq + 4*s5;
        #pragma unroll
        for (int j = 0; j < 4; ++j) {
            int k = k0 + j;
            if (k < KK && fcol < FF)
                out[(size_t)n*KK*FF + k*FF + fcol] = xo[gq][j];
        }
    }

    if (!PHASE) {
        // ---- fused wnorm
        float s = 0.f;
        #pragma unroll
        for (int gq = 0; gq < 4; ++gq) {
            int k0 = Mt2*32 + 8*gq + 4*s5;
            #pragma unroll
            for (int j = 0; j < 4; ++j) {
                if (k0 + j < KK && fcol < FF) {
                    float wn = 1.f / (fabsf(xo[gq][j]) + 0.01f);
                    s += wn * wn;
                }
            }
        }
        #pragma unroll
        for (int off = 32; off > 0; off >>= 1) s += __shfl_down(s, off);
        float* red = (float*)Zs;
        if (l == 0) red[w] = s;
        __syncthreads();
        if (tid == 0) {
            float t = 0.f;
            #pragma unroll
            for (int i = 0; i < 12; ++i) t += red[i];
            atomicAdd(&ws[1], t);
        }
    } else {
        // ---- fused reconst: f16(code) into Ys, GEMM1 pass (+rank-1), store
        #pragma unroll
        for (int gq = 0; gq < 4; ++gq) {
            union { unsigned long long u; _Float16 hh[4]; } yh;
            #pragma unroll
            for (int j = 0; j < 4; ++j) yh.hh[j] = (_Float16)xo[gq][j];
            int yofs = ((gq*16 + cl) << 3) + (s5 << 2);
            *(unsigned long long*)&Ys[SWZY(((nt16*6 + Mt2) << 9) + yofs)] = yh.u;
        }
        __syncthreads();
        f32x4 zz;
        {
            half8 bh = *(const half8*)&Ys[SWZY(((nt1*6 + 0) << 9) + (l << 3))];
            zz = MFMA_16(a1[0][0], bh, z4);
            zz = MFMA_16(a1[0][1], bh, zz);
        }
        #pragma unroll
        for (int kt = 1; kt < 5; ++kt) {
            half8 bh = *(const half8*)&Ys[SWZY(((nt1*6 + kt) << 9) + (l << 3))];
            zz = MFMA_16(a1[kt][0], bh, zz);
            zz = MFMA_16(a1[kt][1], bh, zz);
        }
        {
            float c160 = (float)Ys[y160i];
            #pragma unroll
            for (int r = 0; r < 4; ++r) zz[r] = fmaf(dcol[r], c160, zz[r]);
        }
        int fcol2 = nt1*16 + cl;
        #pragma unroll
        for (int r = 0; r < 4; ++r) {
            int t = Mt1*16 + q*4 + r;
            if (t < TT && fcol2 < FF)
                out[R_OFF + (size_t)n*TT*FF + t*FF + fcol2] = zz[r];
        }
    }
}

// ---------------------------------------------------------------------------
extern "C" void kernel_launch(void* const* d_in, const int* in_sizes, int n_in,
                              void* d_out, int out_size, void* d_ws, size_t ws_size,
                              hipStream_t stream) {
    const float* x  = (const float*)d_in[0];
    const float* rr = (const float*)d_in[1];
    const float* th = (const float*)d_in[2];
    float* out = (float*)d_out;
    float* ws  = (float*)d_ws;

    hipLaunchKernelGGL(k_build, dim3(64), dim3(256), 0, stream, rr, th, out, ws);
    hipLaunchKernelGGL(HIP_KERNEL_NAME(k_fista<0>), dim3(NB), dim3(768), 0, stream, ws, x, out);
    hipLaunchKernelGGL(HIP_KERNEL_NAME(k_fista<1>), dim3(NB), dim3(768), 0, stream, ws, x, out);
}

// Round 6
// 312.103 us; speedup vs baseline: 1.6224x; 1.2012x over previous
//
#include <hip/hip_runtime.h>
#include <math.h>

// Problem constants
#define NB   256
#define TT   36
#define FF   50
#define PP   80
#define KK   161
#define NITER 100
#define LAMB 0.1f

#define CODE_SZ (NB*KK*FF)          // 2,060,800
#define D_OFF   CODE_SZ
#define R_OFF   (CODE_SZ + TT*KK)

// ws float layout:
// [1] = wn^2 accumulator; [16..79] = ssq partials (64 k_build blocks)
// [80..179] = beta momentum table (betas[it], it=1..99)
// [WSA1..] A1 image (D):   [Mt1:3][kt:6][h:2][512] f16 = 9216 floats
// [WSA2..] A2 image (D^T): [Mt2:6][kt:3][h:2][512] f16 = 9216 floats
#define WSA1 256
#define WSA2 (256 + 9216)

typedef _Float16 half8 __attribute__((ext_vector_type(8)));
typedef float f32x4  __attribute__((ext_vector_type(4)));
typedef float f32x16 __attribute__((ext_vector_type(16)));
#define MFMA_16(A,B,C) __builtin_amdgcn_mfma_f32_16x16x32_f16(A,B,C,0,0,0)
#define MFMA_32(A,B,C) __builtin_amdgcn_mfma_f32_32x32x16_f16(A,B,C,0,0,0)

// ---------------------------------------------------------------------------
// K1 (grid 64): build D (blk0 -> d_out), ssq partials -> ws[16+b], beta table
// (blk0 lane0 -> ws[80..179]), pack f16 hi/lo MFMA A-operand images for D
// (GEMM1 16x16x32) and D^T (GEMM2 32x32x16).
__global__ __launch_bounds__(256) void k_build(const float* __restrict__ rr,
                                               const float* __restrict__ th,
                                               float* __restrict__ out,
                                               float* __restrict__ ws) {
    __shared__ float Dl[TT*KK];
    __shared__ float red[256];
    int tid = threadIdx.x, b = blockIdx.x;
    for (int e = tid; e < TT*KK; e += 256) {
        int t = e / KK, k = e % KK;
        float v;
        if (k == 0) v = 1.f;
        else if (k <= PP) { int p = k - 1;     v = powf(rr[p], (float)t) * cosf((float)t * th[p]); }
        else              { int p = k - 1 - PP; v = powf(rr[p], (float)t) * sinf((float)t * th[p]); }
        Dl[e] = v;
        if (b == 0) out[D_OFF + e] = v;
    }
    // beta momentum table: identical float ops to the original in-loop chain
    if (b == 0 && tid == 0) {
        float t = 0.5f * (1.f + sqrtf(5.f));   // t_1 (after peeled iter 0)
        ws[80] = 0.f;
        for (int it = 1; it < NITER; ++it) {
            float tn = 0.5f * (1.f + sqrtf(1.f + 4.f*t*t));
            ws[80 + it] = (t - 1.f) / tn;
            t = tn;
        }
    }
    __syncthreads();
    float ssq = 0.f;
    for (int p = b*256 + tid; p < KK*KK; p += 64*256) {
        int k1 = p / KK, k2 = p % KK;
        float s = 0.f;
        for (int t = 0; t < TT; ++t) s += Dl[t*KK + k1] * Dl[t*KK + k2];
        ssq += s * s;
    }
    red[tid] = ssq;
    __syncthreads();
    for (int off = 128; off > 0; off >>= 1) {
        if (tid < off) red[tid] += red[tid + off];
        __syncthreads();
    }
    if (tid == 0) { ws[16 + b] = red[0]; if (b == 0) ws[1] = 0.f; }

    // A1: lane l holds A[m=l&15][k=8*(l>>4)+i] per 16x16x32 tile
    _Float16* a1 = (_Float16*)(ws + WSA1);
    for (int e = b*256 + tid; e < 3*6*2*512; e += 64*256) {
        int fp = e & 511, r = e >> 9;       // r = (Mt1*6+kt)*2 + h
        int h = r & 1, mk = r >> 1;
        int l = fp >> 3, i = fp & 7;
        int t = (mk / 6) * 16 + (l & 15);
        int j = (mk % 6) * 32 + ((l >> 4) << 3) + i;
        float v = (t < TT && j < KK) ? Dl[t*KK + j] : 0.f;
        _Float16 hi = (_Float16)v;
        a1[e] = h ? (_Float16)(v - (float)hi) : hi;
    }
    // A2 (D^T): lane l holds A[m=l&31][k=8*(l>>5)+i] per 32x32x16 tile
    _Float16* a2 = (_Float16*)(ws + WSA2);
    for (int e = b*256 + tid; e < 6*3*2*512; e += 64*256) {
        int fp = e & 511, r = e >> 9;       // r = (Mt2*3+kt)*2 + h
        int h = r & 1, mk = r >> 1;
        int l = fp >> 3, i = fp & 7;
        int m = (mk / 3) * 32 + (l & 31);
        int t = (mk % 3) * 16 + ((l >> 5) << 3) + i;
        float v = (m < KK && t < TT) ? Dl[t*KK + m] : 0.f;
        _Float16 hi = (_Float16)v;
        a2[e] = h ? (_Float16)(v - (float)hi) : hi;
    }
}

// ---------------------------------------------------------------------------
// K2: fused FISTA, grid 256 (one n per block), 768 threads = 12 waves.
// R5 lesson: cutting LDS bytes at the cost of added VALU+latency regresses ->
// issue-cycle-sum model (time/iter ~ MFMA-issue + VALU-issue + ~340cyc
// barrier overhead). This round: drop the lo-correction MFMAs INSIDE the
// iteration loop only (6+3 fewer MFMAs/wave/iter, -162 of 324 MFMA
// issue-cyc/SIMD). Head (DtY) and reconst tail keep full hi+lo precision.
// Iteration operator precision ~1e-3 rel; FISTA is contractive so the
// perturbation saturates. Clean single-variable A/B vs the R2 config.
// GEMM1 (z = D y): 16x16x32, wave = (Mt1 = w>>2, nt1 = w&3).
// GEMM2 (w = D^T z): 32x32x16, wave = (Mt2 = w>>1, nh = w&1).
template<int PHASE>
__global__ __launch_bounds__(768, 3) void k_fista(float* __restrict__ ws,
                                                  const float* __restrict__ x,
                                                  float* __restrict__ out) {
    __shared__ _Float16 Ys[4*6*512];   // 24,576 B: [nt16:4][kt32:6][512]
    __shared__ _Float16 Zs[2*3*512];   //  6,144 B: [nh:2][kt16:3][512]
    __shared__ float bts[NITER];       //    400 B: beta momentum table
    int tid = threadIdx.x;
    int w = tid >> 6, l = tid & 63;
    int n = blockIdx.x;

    // ---- stage x -> Zs (f16 hi, GEMM2 B-frag image, k-dim = t)
    const float* xb = x + n*TT*FF;
    for (int e = tid; e < 3072; e += 768) {
        int t = e >> 6, c64 = e & 63;
        float v = (t < TT && c64 < FF) ? xb[t*FF + c64] : 0.f;
        int nh = c64 >> 5, c = c64 & 31;
        int kt = t >> 4, kk = t & 15;
        int ofs = ((((kk >> 3) << 5) + c) << 3) + (kk & 7);
        Zs[((nh*3 + kt) << 9) + ofs] = (_Float16)v;
    }
    if (tid < NITER) bts[tid] = ws[80 + tid];

    // ---- L-norm: wave butterfly over the 64 k_build partials
    float pv = ws[16 + l];
    #pragma unroll
    for (int off = 32; off > 0; off >>= 1) pv += __shfl_xor(pv, off);
    float linv = rsqrtf(pv);

    int Mt1 = w >> 2, nt1 = w & 3;     // GEMM1 role
    int Mt2 = w >> 1, nh  = w & 1;     // GEMM2 role
    const _Float16* a1g = (const _Float16*)(ws + WSA1);
    const _Float16* a2g = (const _Float16*)(ws + WSA2);
    half8 a1[6][2], a2[3][2];
    #pragma unroll
    for (int kt = 0; kt < 6; ++kt)
        #pragma unroll
        for (int h = 0; h < 2; ++h)
            a1[kt][h] = *(const half8*)(a1g + ((((Mt1*6 + kt)*2 + h) << 9) + (l << 3)));
    #pragma unroll
    for (int kt = 0; kt < 3; ++kt)
        #pragma unroll
        for (int h = 0; h < 2; ++h)
            a2[kt][h] = *(const half8*)(a2g + ((((Mt2*3 + kt)*2 + h) << 9) + (l << 3)));

    // held zero accumulators (loop-invariant C operands for first MFMA)
    f32x16 z16;
    #pragma unroll
    for (int r = 0; r < 16; ++r) z16[r] = 0.f;
    f32x4 z4 = {0.f, 0.f, 0.f, 0.f};
    __syncthreads();

    // ---- head GEMM2: acc = D^T @ f16(x)  (hi+lo, full precision for c)
    f32x16 acc;
    {
        half8 bh = *(const half8*)&Zs[((nh*3 + 0) << 9) + (l << 3)];
        acc = MFMA_32(a2[0][0], bh, z16);
        acc = MFMA_32(a2[0][1], bh, acc);
    }
    #pragma unroll
    for (int kt = 1; kt < 3; ++kt) {
        half8 bh = *(const half8*)&Zs[((nh*3 + kt) << 9) + (l << 3)];
        acc = MFMA_32(a2[kt][0], bh, acc);
        acc = MFMA_32(a2[kt][1], bh, acc);
    }

    int cl = l & 15, q = l >> 4;       // GEMM1 C addressing
    int nloc = l & 31, s5 = l >> 5;    // GEMM2 C addressing
    int nt16 = nh*2 + (nloc >> 4);
    int fcol = nh*32 + nloc;           // global f of owned columns
    int zofs = ((((q >> 1) << 5) + (nt1 & 1)*16 + cl) << 3) + ((q & 1) << 2);
    int znh = nt1 >> 1;
    float cv[4][4], wl[4][4], xo[4][4], yo[4][4];
    float wlv = LAMB * linv;           // uniform shrink width (phase 0)

    // ---- peeled iteration 0: x1 = shrink(c), y1 = x1
    {
        float fac = 0.f;
        if (PHASE) fac = (float)KK * LAMB * linv * rsqrtf(ws[1]);
        #pragma unroll
        for (int gq = 0; gq < 4; ++gq) {
            int k0 = Mt2*32 + 8*gq + 4*s5;
            union { unsigned long long u; _Float16 hh[4]; } yh;
            #pragma unroll
            for (int j = 0; j < 4; ++j) {
                int k = k0 + j;
                float cvv = 0.f, wle;
                if (PHASE) {
                    wle = 0.f;
                    if (k < KK && fcol < FF) {
                        cvv = linv * acc[gq*4 + j];
                        float prev = out[(size_t)n*KK*FF + k*FF + fcol];
                        wle = fac / (fabsf(prev) + 0.01f);
                    }
                    wl[gq][j] = wle;
                } else {
                    wle = wlv;
                    if (k < KK && fcol < FF) cvv = linv * acc[gq*4 + j];
                }
                cv[gq][j] = cvv;
                float xn = cvv - __builtin_amdgcn_fmed3f(cvv, -wle, wle);
                xo[gq][j] = xn; yo[gq][j] = xn;
                yh.hh[j] = (_Float16)xn;
            }
            int yofs = ((gq*16 + cl) << 3) + (s5 << 2);
            *(unsigned long long*)&Ys[((nt16*6 + Mt2) << 9) + yofs] = yh.u;
        }
    }
    __syncthreads();

    for (int it = 1; it < NITER; ++it) {
        float beta = bts[it];
        // ---- GEMM1: z(Mt1, nt1) = D_hi @ f16(y)  (hi-only in-loop)
        f32x4 zz;
        {
            half8 bh = *(const half8*)&Ys[((nt1*6 + 0) << 9) + (l << 3)];
            zz = MFMA_16(a1[0][0], bh, z4);
        }
        #pragma unroll
        for (int kt = 1; kt < 6; ++kt) {
            half8 bh = *(const half8*)&Ys[((nt1*6 + kt) << 9) + (l << 3)];
            zz = MFMA_16(a1[kt][0], bh, zz);
        }
        {
            union { unsigned long long u; _Float16 hh[4]; } ph;
            #pragma unroll
            for (int r = 0; r < 4; ++r) ph.hh[r] = (_Float16)zz[r];
            *(unsigned long long*)&Zs[((znh*3 + Mt1) << 9) + zofs] = ph.u;
        }
        __syncthreads();

        // ---- GEMM2: acc(Mt2, nh) = D_hi^T @ f16(z)  (hi-only in-loop)
        {
            half8 bh = *(const half8*)&Zs[((nh*3 + 0) << 9) + (l << 3)];
            acc = MFMA_32(a2[0][0], bh, z16);
        }
        #pragma unroll
        for (int kt = 1; kt < 3; ++kt) {
            half8 bh = *(const half8*)&Zs[((nh*3 + kt) << 9) + (l << 3)];
            acc = MFMA_32(a2[kt][0], bh, acc);
        }
        // ---- epilogue: med3 shrink + momentum, rebuild y image (f16 hi)
        #pragma unroll
        for (int gq = 0; gq < 4; ++gq) {
            union { unsigned long long u; _Float16 hh[4]; } yh;
            #pragma unroll
            for (int j = 0; j < 4; ++j) {
                float ay = fmaf(-linv, acc[gq*4 + j], yo[gq][j]);
                float u  = ay + cv[gq][j];
                float wle = PHASE ? wl[gq][j] : wlv;
                float xn = u - __builtin_amdgcn_fmed3f(u, -wle, wle);
                float yn = fmaf(beta, xn - xo[gq][j], xn);
                xo[gq][j] = xn; yo[gq][j] = yn;
                yh.hh[j] = (_Float16)yn;
            }
            int yofs = ((gq*16 + cl) << 3) + (s5 << 2);
            *(unsigned long long*)&Ys[((nt16*6 + Mt2) << 9) + yofs] = yh.u;
        }
        __syncthreads();
    }

    // ---- store final code
    #pragma unroll
    for (int gq = 0; gq < 4; ++gq) {
        int k0 = Mt2*32 + 8*gq + 4*s5;
        #pragma unroll
        for (int j = 0; j < 4; ++j) {
            int k = k0 + j;
            if (k < KK && fcol < FF)
                out[(size_t)n*KK*FF + k*FF + fcol] = xo[gq][j];
        }
    }

    if (!PHASE) {
        // ---- fused wnorm
        float s = 0.f;
        #pragma unroll
        for (int gq = 0; gq < 4; ++gq) {
            int k0 = Mt2*32 + 8*gq + 4*s5;
            #pragma unroll
            for (int j = 0; j < 4; ++j) {
                if (k0 + j < KK && fcol < FF) {
                    float wn = 1.f / (fabsf(xo[gq][j]) + 0.01f);
                    s += wn * wn;
                }
            }
        }
        #pragma unroll
        for (int off = 32; off > 0; off >>= 1) s += __shfl_down(s, off);
        float* red = (float*)Zs;
        if (l == 0) red[w] = s;
        __syncthreads();
        if (tid == 0) {
            float t = 0.f;
            #pragma unroll
            for (int i = 0; i < 12; ++i) t += red[i];
            atomicAdd(&ws[1], t);
        }
    } else {
        // ---- fused reconst: f16(code) into Ys, GEMM1 pass (hi+lo), store
        #pragma unroll
        for (int gq = 0; gq < 4; ++gq) {
            union { unsigned long long u; _Float16 hh[4]; } yh;
            #pragma unroll
            for (int j = 0; j < 4; ++j) yh.hh[j] = (_Float16)xo[gq][j];
            int yofs = ((gq*16 + cl) << 3) + (s5 << 2);
            *(unsigned long long*)&Ys[((nt16*6 + Mt2) << 9) + yofs] = yh.u;
        }
        __syncthreads();
        f32x4 za, zb;
        {
            half8 bh = *(const half8*)&Ys[((nt1*6 + 0) << 9) + (l << 3)];
            za = MFMA_16(a1[0][0], bh, z4);
            zb = MFMA_16(a1[0][1], bh, z4);
        }
        #pragma unroll
        for (int kt = 1; kt < 6; ++kt) {
            half8 bh = *(const half8*)&Ys[((nt1*6 + kt) << 9) + (l << 3)];
            za = MFMA_16(a1[kt][0], bh, za);
            zb = MFMA_16(a1[kt][1], bh, zb);
        }
        f32x4 zz = za + zb;
        int fcol2 = nt1*16 + cl;
        #pragma unroll
        for (int r = 0; r < 4; ++r) {
            int t = Mt1*16 + q*4 + r;
            if (t < TT && fcol2 < FF)
                out[R_OFF + (size_t)n*TT*FF + t*FF + fcol2] = zz[r];
        }
    }
}

// ---------------------------------------------------------------------------
extern "C" void kernel_launch(void* const* d_in, const int* in_sizes, int n_in,
                              void* d_out, int out_size, void* d_ws, size_t ws_size,
                              hipStream_t stream) {
    const float* x  = (const float*)d_in[0];
    const float* rr = (const float*)d_in[1];
    const float* th = (const float*)d_in[2];
    float* out = (float*)d_out;
    float* ws  = (float*)d_ws;

    hipLaunchKernelGGL(k_build, dim3(64), dim3(256), 0, stream, rr, th, out, ws);
    hipLaunchKernelGGL(HIP_KERNEL_NAME(k_fista<0>), dim3(NB), dim3(768), 0, stream, ws, x, out);
    hipLaunchKernelGGL(HIP_KERNEL_NAME(k_fista<1>), dim3(NB), dim3(768), 0, stream, ws, x, out);
}